// Round 2
// baseline (218.502 us; speedup 1.0000x reference)
//
#include <hip/hip_runtime.h>
#include <math.h>

// 2D IDCT 4096x4096.
// colA: Z-build + 32-pt register FFT, 1 column/thread; x staged through LDS
//       via double-buffered global_load_lds (16B/lane), no spills.
// colB: 64-pt FFT split 2 threads via DIT (two 32-pt reg FFTs + LDS combine).
// rows: in-place LDS Stockham radix-8/8/8/4 with float4 staged I/O.

#define TT 256

constexpr float W64R[32] = {
    1.0f, 0.995184726672197f, 0.980785280403230f, 0.956940335732209f,
    0.923879532511287f, 0.881921264348355f, 0.831469612302545f, 0.773010453362737f,
    0.707106781186548f, 0.634393284163645f, 0.555570233019602f, 0.471396736825998f,
    0.382683432365090f, 0.290284677254462f, 0.195090322016128f, 0.0980171403295606f,
    0.0f, -0.0980171403295606f, -0.195090322016128f, -0.290284677254462f,
    -0.382683432365090f, -0.471396736825998f, -0.555570233019602f, -0.634393284163645f,
    -0.707106781186548f, -0.773010453362737f, -0.831469612302545f, -0.881921264348355f,
    -0.923879532511287f, -0.956940335732209f, -0.980785280403230f, -0.995184726672197f};
constexpr float W64I[32] = {
    0.0f, 0.0980171403295606f, 0.195090322016128f, 0.290284677254462f,
    0.382683432365090f, 0.471396736825998f, 0.555570233019602f, 0.634393284163645f,
    0.707106781186548f, 0.773010453362737f, 0.831469612302545f, 0.881921264348355f,
    0.923879532511287f, 0.956940335732209f, 0.980785280403230f, 0.995184726672197f,
    1.0f, 0.995184726672197f, 0.980785280403230f, 0.956940335732209f,
    0.923879532511287f, 0.881921264348355f, 0.831469612302545f, 0.773010453362737f,
    0.707106781186548f, 0.634393284163645f, 0.555570233019602f, 0.471396736825998f,
    0.382683432365090f, 0.290284677254462f, 0.195090322016128f, 0.0980171403295606f};

__device__ __forceinline__ constexpr int brev(int x, int bits) {
    int r = 0;
    for (int i = 0; i < bits; ++i) { r = (r << 1) | (x & 1); x >>= 1; }
    return r;
}

__device__ __forceinline__ float vadd(float a, float b) { return a + b; }
__device__ __forceinline__ float vsub(float a, float b) { return a - b; }
__device__ __forceinline__ float vmul(float a, float s) { return a * s; }
__device__ __forceinline__ float2 vadd(float2 a, float2 b) { return make_float2(a.x + b.x, a.y + b.y); }
__device__ __forceinline__ float2 vsub(float2 a, float2 b) { return make_float2(a.x - b.x, a.y - b.y); }
__device__ __forceinline__ float2 vmul(float2 a, float s) { return make_float2(a.x * s, a.y * s); }

// in-register DIF FFT (sign +), output bit-reversed: re/im[j] = z[brev(j)]
template <int NP, typename V>
__device__ __forceinline__ void fft_dif(V* re, V* im) {
#pragma unroll
    for (int h = NP / 2; h >= 1; h >>= 1) {
#pragma unroll
        for (int b = 0; b < NP; b += 2 * h) {
#pragma unroll
            for (int k = 0; k < h; ++k) {
                V ur = re[b + k], ui = im[b + k];
                V vr = re[b + k + h], vi = im[b + k + h];
                V dr = vsub(ur, vr), di = vsub(ui, vi);
                re[b + k] = vadd(ur, vr);
                im[b + k] = vadd(ui, vi);
                float wr = W64R[k * (32 / h)], wi = W64I[k * (32 / h)];
                re[b + k + h] = vsub(vmul(dr, wr), vmul(di, wi));
                im[b + k + h] = vadd(vmul(dr, wi), vmul(di, wr));
            }
        }
    }
}

// ---- init: tw2048[k]=e^{2pi i k/2048}; Z coeff tables (double precision) --
__global__ void tw_init_kernel(float2* __restrict__ tw2048,
                               float2* __restrict__ ca, float2* __restrict__ cb,
                               float2* __restrict__ cc, float2* __restrict__ cd) {
    int k = blockIdx.x * TT + threadIdx.x;   // 8 blocks x 256 = 2048
    const double s = 0.5 / 4096.0;
    double aw = M_PI * (double)k / 2048.0;
    double wr = cos(aw), wi = sin(aw);
    double a1 = M_PI * (double)k / 8192.0;
    double e1r = cos(a1), e1i = sin(a1);
    double a2 = M_PI * (double)(k + 2048) / 8192.0;
    double e2r = cos(a2), e2i = sin(a2);
    double Ar = s * ((1.0 - wi) * e1r - wr * e1i);
    double Ai = s * ((1.0 - wi) * e1i + wr * e1r);
    double Br = (k == 0) ? 0.0 : Ai;
    double Bi = (k == 0) ? 0.0 : -Ar;
    double Cr = s * ((1.0 + wi) * e2r + wr * e2i);
    double Ci = s * ((1.0 + wi) * e2i - wr * e2r);
    ca[k] = make_float2((float)Ar, (float)Ai);
    cb[k] = make_float2((float)Br, (float)Bi);
    cc[k] = make_float2((float)Cr, (float)Ci);
    cd[k] = make_float2((float)Ci, (float)-Cr);
    double at = M_PI * (double)k / 1024.0;
    tw2048[k] = make_float2((float)cos(at), (float)sin(at));
}

// ---- column pass A: 1 column/thread, 32-pt FFT; LDS-staged float4 loads ---
// grid (16,64) x 256: block = 256 cols x 1 k1. Per chunk, 16 rows x 256 cols
// (16 KB) staged via global_load_lds width=16; double-buffered, __syncthreads
// at loop top drains only the chunk being consumed (next chunk issued after).
typedef __attribute__((address_space(1))) const unsigned int* ga_u32;
typedef __attribute__((address_space(3))) unsigned int* la_u32;

#define COLA_STAGE(CH)                                                          \
    do {                                                                        \
        const int _b = (CH) & 1;                                                \
        _Pragma("unroll") for (int v = 0; v < 4; ++v) {                         \
            int k = k1 + 64 * ((CH) * 4 + v);                                   \
            int row = (w == 0) ? k                                              \
                    : (w == 1) ? ((4096 - k) & 4095)                            \
                    : (w == 2) ? (2048 + k)                                     \
                               : (2048 - k);                                    \
            __builtin_amdgcn_global_load_lds(                                   \
                (ga_u32)(const void*)(x + (size_t)row * 4096 + colb + 4 * l),   \
                (la_u32)(void*)&stg[_b][v * 4 + w][4 * l], 16, 0, 0);           \
        }                                                                       \
    } while (0)

__global__ __launch_bounds__(TT) void col_a_kernel(
    const float* __restrict__ x,
    const float2* __restrict__ ca, const float2* __restrict__ cb,
    const float2* __restrict__ cc, const float2* __restrict__ cd,
    const float2* __restrict__ tw2048, float2* __restrict__ T1) {
    __shared__ float stg[2][16][256];   // 32 KB
    const int tx = threadIdx.x;
    const int w = tx >> 6;              // wave id == Z-term id
    const int l = tx & 63;
    const int k1 = blockIdx.y;          // [0,64)
    const int colb = blockIdx.x << 8;   // column base
    float fr[32], fi[32];

    COLA_STAGE(0);
#pragma unroll
    for (int ch = 0; ch < 8; ++ch) {
        __syncthreads();                 // drains my chunk-ch loads + barrier
        if (ch + 1 < 8) COLA_STAGE(ch + 1);   // async into other buffer
        const int b = ch & 1;
#pragma unroll
        for (int v = 0; v < 4; ++v) {
            int k2 = ch * 4 + v;
            int k = k1 + 64 * k2;        // wave-uniform -> scalar coeff loads
            float xa = stg[b][v * 4 + 0][tx];
            float xb = stg[b][v * 4 + 1][tx];
            float xc = stg[b][v * 4 + 2][tx];
            float xd = stg[b][v * 4 + 3][tx];
            float2 A = ca[k], B = cb[k], C = cc[k], D = cd[k];
            fr[k2] = A.x * xa + B.x * xb + C.x * xc + D.x * xd;
            fi[k2] = A.y * xa + B.y * xb + C.y * xc + D.y * xd;
        }
    }
    fft_dif<32, float>(fr, fi);
#pragma unroll
    for (int j = 0; j < 32; ++j) {
        int n2 = brev(j, 5);
        float2 wv = tw2048[k1 * n2];
        float2 o = make_float2(fr[j] * wv.x - fi[j] * wv.y,
                               fr[j] * wv.y + fi[j] * wv.x);
        T1[(size_t)(k1 * 32 + n2) * 4096 + colb + tx] = o;
    }
}

// ---- column pass B: 64-pt FFT as DIT, 2 threads/FFT (two 32-pt reg FFTs) --
// grid (64,16) x block (64,4): ty&1 = parity tz, ty>>1 = n2 sub-group.
// z[n]    = E[n] + W64^n O[n]   (tz=0 stores n1 = n)
// z[n+32] = E[n] - W64^n O[n]   (tz=1 stores n1 = n+32)
__global__ __launch_bounds__(TT) void col_b_kernel(
    const float2* __restrict__ T1, float* __restrict__ out) {
    __shared__ float2 EO[2][32][64];   // 32 KB, shared by the two g-groups
    int tx = threadIdx.x;
    int ty = threadIdx.y;
    int tz = ty & 1;                   // even/odd k1 parity
    int g  = ty >> 1;                  // local n2 sub-index
    int c = blockIdx.x * 64 + tx;
    int n2 = blockIdx.y * 2 + g;
    float fr[32], fi[32];
#pragma unroll
    for (int a = 0; a < 32; ++a) {
        int k1 = 2 * a + tz;
        float2 v = T1[(size_t)(k1 * 32 + n2) * 4096 + c];
        fr[a] = v.x; fi[a] = v.y;
    }
    fft_dif<32, float>(fr, fi);        // E (tz=0) or O (tz=1), bit-reversed j
#pragma unroll
    for (int gg = 0; gg < 2; ++gg) {
        if (g == gg) {
#pragma unroll
            for (int j = 0; j < 32; ++j) {
                int n = brev(j, 5);
                float vr = fr[j], vi = fi[j];
                if (tz) {              // apply W64^n to the odd branch
                    float wr = W64R[n], wi = W64I[n];
                    float t2 = vr * wr - vi * wi;
                    vi = vr * wi + vi * wr;
                    vr = t2;
                }
                EO[tz][n][tx] = make_float2(vr, vi);
            }
        }
        __syncthreads();
        if (g == gg) {
#pragma unroll
            for (int n = 0; n < 32; ++n) {
                float2 E  = EO[0][n][tx];
                float2 WO = EO[1][n][tx];
                float zr, zi;
                if (tz == 0) { zr = E.x + WO.x; zi = E.y + WO.y; }
                else         { zr = E.x - WO.x; zi = E.y - WO.y; }
                int n1 = tz * 32 + n;
                int m = 32 * n1 + n2;
                int r_re = (n1 < 32) ? 4 * m     : 8191 - 4 * m;
                int r_im = (n1 < 32) ? 4 * m + 2 : 8189 - 4 * m;
                out[(size_t)r_re * 4096 + c] = zr;
                out[(size_t)r_im * 4096 + c] = zi;
            }
        }
        __syncthreads();
    }
}

// ---- radix-8 DFT (sign +) --------------------------------------------------
#define C_SQ2 0.70710678118654752440f
__device__ __forceinline__ void radix8(const float* ar, const float* ai,
                                       float* tr, float* ti) {
    float s04r = ar[0] + ar[4], s04i = ai[0] + ai[4];
    float d04r = ar[0] - ar[4], d04i = ai[0] - ai[4];
    float s26r = ar[2] + ar[6], s26i = ai[2] + ai[6];
    float d26r = ar[2] - ar[6], d26i = ai[2] - ai[6];
    float E0r = s04r + s26r, E0i = s04i + s26i;
    float E1r = d04r - d26i, E1i = d04i + d26r;
    float E2r = s04r - s26r, E2i = s04i - s26i;
    float E3r = d04r + d26i, E3i = d04i - d26r;
    float s15r = ar[1] + ar[5], s15i = ai[1] + ai[5];
    float d15r = ar[1] - ar[5], d15i = ai[1] - ai[5];
    float s37r = ar[3] + ar[7], s37i = ai[3] + ai[7];
    float d37r = ar[3] - ar[7], d37i = ai[3] - ai[7];
    float O0r = s15r + s37r, O0i = s15i + s37i;
    float O1r = d15r - d37i, O1i = d15i + d37r;
    float O2r = s15r - s37r, O2i = s15i - s37i;
    float O3r = d15r + d37i, O3i = d15i - d37r;
    float W1r = C_SQ2 * (O1r - O1i), W1i = C_SQ2 * (O1r + O1i);
    float W2r = -O2i, W2i = O2r;
    float W3r = -C_SQ2 * (O3r + O3i), W3i = C_SQ2 * (O3r - O3i);
    tr[0] = E0r + O0r; ti[0] = E0i + O0i;
    tr[4] = E0r - O0r; ti[4] = E0i - O0i;
    tr[1] = E1r + W1r; ti[1] = E1i + W1i;
    tr[5] = E1r - W1r; ti[5] = E1i - W1i;
    tr[2] = E2r + W2r; ti[2] = E2i + W2i;
    tr[6] = E2r - W2r; ti[6] = E2i - W2i;
    tr[3] = E3r + W3r; ti[3] = E3i + W3i;
    tr[7] = E3r - W3r; ti[7] = E3i - W3i;
}

// ---- row pass: in-place per-row IDCT, float4 staged I/O -------------------
// pool: b0r[2112] b0i[2112] b1r[2176] b1i[2176]; staging overlays b1 region.
__global__ __launch_bounds__(TT) void idct_rows_kernel(
    const float2* __restrict__ ca, const float2* __restrict__ cb,
    const float2* __restrict__ cc, const float2* __restrict__ cd,
    const float2* __restrict__ tw2048, float* __restrict__ io) {
    __shared__ float pool[8576];
    float* b0r = pool;
    float* b0i = pool + 2112;
    float* b1r = pool + 4224;
    float* b1i = pool + 6400;
    float* stg = pool + 4224;   // 4096 floats, overlays b1 (free until stage B)
    const int t = threadIdx.x;
    float* __restrict__ xr = io + (size_t)blockIdx.x * 4096;

    // stage the row via float4 loads
#pragma unroll
    for (int u = 0; u < 4; ++u) {
        int idx = t + 256 * u;
        float4 v = ((const float4*)xr)[idx];
        *(float4*)&stg[4 * idx] = v;
    }
    __syncthreads();

    float zr[8], zi[8], tr[8], ti[8];
#pragma unroll
    for (int p = 0; p < 8; ++p) {
        int k = t + 256 * p;
        float xa = stg[k];
        float xb = stg[(4096 - k) & 4095];
        float xc = stg[2048 + k];
        float xd = stg[2048 - k];
        float2 A = ca[k], B = cb[k], C = cc[k], D = cd[k];
        zr[p] = A.x * xa + B.x * xb + C.x * xc + D.x * xd;
        zi[p] = A.y * xa + B.y * xb + C.y * xc + D.y * xd;
    }
    // stage A: m=1, j=t; write b0 at 8t+q+(t>>2)
    radix8(zr, zi, tr, ti);
    {
        int baseA = 8 * t + (t >> 2);
        b0r[baseA] = tr[0]; b0i[baseA] = ti[0];
#pragma unroll
        for (int q = 1; q < 8; ++q) {
            float2 w = tw2048[(t * q) & 2047];
            b0r[baseA + q] = w.x * tr[q] - w.y * ti[q];
            b0i[baseA + q] = w.x * ti[q] + w.y * tr[q];
        }
    }
    __syncthreads();
    // stage B: m=8; read b0 (t+(t>>5))+264p, write b1 68j+k +8q+(q>>1)
    {
        float ar[8], ai[8];
        int rb = t + (t >> 5);
#pragma unroll
        for (int p = 0; p < 8; ++p) { ar[p] = b0r[rb + 264 * p]; ai[p] = b0i[rb + 264 * p]; }
        radix8(ar, ai, tr, ti);
        int j = t >> 3, k = t & 7, wj = 8 * j;
        int baseB = 68 * j + k;
        b1r[baseB] = tr[0]; b1i[baseB] = ti[0];
#pragma unroll
        for (int q = 1; q < 8; ++q) {
            int off = baseB + 8 * q + (q >> 1);
            float2 w = tw2048[(wj * q) & 2047];
            b1r[off] = w.x * tr[q] - w.y * ti[q];
            b1i[off] = w.x * ti[q] + w.y * tr[q];
        }
    }
    __syncthreads();
    // stage C: m=64; read b1 (t+(t>>4))+272p, write b0 528j+66q+k+(k>>5)
    {
        float ar[8], ai[8];
        int rb = t + (t >> 4);
#pragma unroll
        for (int p = 0; p < 8; ++p) { ar[p] = b1r[rb + 272 * p]; ai[p] = b1i[rb + 272 * p]; }
        radix8(ar, ai, tr, ti);
        int j = t >> 6, wj = 64 * j, k = t & 63;
        int baseC = 528 * j + k + (k >> 5);
        b0r[baseC] = tr[0]; b0i[baseC] = ti[0];
#pragma unroll
        for (int q = 1; q < 8; ++q) {
            int off = baseC + 66 * q;
            float2 w = tw2048[(wj * q) & 2047];
            b0r[off] = w.x * tr[q] - w.y * ti[q];
            b0i[off] = w.x * ti[q] + w.y * tr[q];
        }
    }
    __syncthreads();
    // stage D: m=512 radix-4, tw=1; read b0 (b+(b>>5))+528s, write b1 (b+(b>>4))+544s
#pragma unroll
    for (int u = 0; u < 2; ++u) {
        int b = t + 256 * u;
        int rb = b + (b >> 5);
        int wb = b + (b >> 4);
        float a0r = b0r[rb], a0i = b0i[rb];
        float a1r = b0r[rb + 528], a1i = b0i[rb + 528];
        float a2r = b0r[rb + 1056], a2i = b0i[rb + 1056];
        float a3r = b0r[rb + 1584], a3i = b0i[rb + 1584];
        float s02r = a0r + a2r, s02i = a0i + a2i;
        float d02r = a0r - a2r, d02i = a0i - a2i;
        float s13r = a1r + a3r, s13i = a1i + a3i;
        float d13r = a1r - a3r, d13i = a1i - a3i;
        b1r[wb] = s02r + s13r;          b1i[wb] = s02i + s13i;
        b1r[wb + 544] = d02r - d13i;    b1i[wb + 544] = d02i + d13r;
        b1r[wb + 1088] = s02r - s13r;   b1i[wb + 1088] = s02i - s13i;
        b1r[wb + 1632] = d02r + d13i;   b1i[wb + 1632] = d02i - d13r;
    }
    __syncthreads();
    // epilogue: out[4s..4s+3] = {Re z[s], Im z[2047-s], Im z[s], Re z[2047-s]}
#pragma unroll
    for (int i = 0; i < 4; ++i) {
        int s = t + 256 * i;
        int l2 = 2047 - s;
        int ms = s + (s >> 4);
        int ml = l2 + (l2 >> 4);
        float4 o = make_float4(b1r[ms], b1i[ml], b1i[ms], b1r[ml]);
        *(float4*)&xr[4 * s] = o;
    }
}

extern "C" void kernel_launch(void* const* d_in, const int* in_sizes, int n_in,
                              void* d_out, int out_size, void* d_ws, size_t ws_size,
                              hipStream_t stream) {
    const float* x = (const float*)d_in[0];
    float* out = (float*)d_out;

    float2* tw2048 = (float2*)d_ws;
    float2* ca = (float2*)((char*)d_ws + 1 * 16384);
    float2* cb = (float2*)((char*)d_ws + 2 * 16384);
    float2* cc = (float2*)((char*)d_ws + 3 * 16384);
    float2* cd = (float2*)((char*)d_ws + 4 * 16384);
    float2* T1 = (float2*)((char*)d_ws + (1 << 20));   // 64 MB

    tw_init_kernel<<<8, TT, 0, stream>>>(tw2048, ca, cb, cc, cd);
    col_a_kernel<<<dim3(16, 64), TT, 0, stream>>>(x, ca, cb, cc, cd, tw2048, T1);
    col_b_kernel<<<dim3(64, 16), dim3(64, 4), 0, stream>>>(T1, out);
    idct_rows_kernel<<<4096, TT, 0, stream>>>(ca, cb, cc, cd, tw2048, out);
}

// Round 3
// 195.209 us; speedup vs baseline: 1.1193x; 1.1193x over previous
//
#include <hip/hip_runtime.h>
#include <math.h>

// 2D IDCT 4096x4096.
// colA: Z-build + 32-pt register FFT, 1 column/thread, direct global loads,
//       no LDS, no barriers; launch_bounds(256,1) so the allocator does NOT
//       squeeze below the 64 live fr/fi registers (round-1 spill trap).
// colB: 64-pt FFT as DIT split across the two halves of one wave
//       (lane l <-> l+32 = even/odd k1 of the SAME column); combine via
//       __shfl_xor, no LDS, no barriers, no idle lanes.
// rows: in-place LDS Stockham radix-8/8/8/4 with float4 staged I/O.

#define TT 256

constexpr float W64R[32] = {
    1.0f, 0.995184726672197f, 0.980785280403230f, 0.956940335732209f,
    0.923879532511287f, 0.881921264348355f, 0.831469612302545f, 0.773010453362737f,
    0.707106781186548f, 0.634393284163645f, 0.555570233019602f, 0.471396736825998f,
    0.382683432365090f, 0.290284677254462f, 0.195090322016128f, 0.0980171403295606f,
    0.0f, -0.0980171403295606f, -0.195090322016128f, -0.290284677254462f,
    -0.382683432365090f, -0.471396736825998f, -0.555570233019602f, -0.634393284163645f,
    -0.707106781186548f, -0.773010453362737f, -0.831469612302545f, -0.881921264348355f,
    -0.923879532511287f, -0.956940335732209f, -0.980785280403230f, -0.995184726672197f};
constexpr float W64I[32] = {
    0.0f, 0.0980171403295606f, 0.195090322016128f, 0.290284677254462f,
    0.382683432365090f, 0.471396736825998f, 0.555570233019602f, 0.634393284163645f,
    0.707106781186548f, 0.773010453362737f, 0.831469612302545f, 0.881921264348355f,
    0.923879532511287f, 0.956940335732209f, 0.980785280403230f, 0.995184726672197f,
    1.0f, 0.995184726672197f, 0.980785280403230f, 0.956940335732209f,
    0.923879532511287f, 0.881921264348355f, 0.831469612302545f, 0.773010453362737f,
    0.707106781186548f, 0.634393284163645f, 0.555570233019602f, 0.471396736825998f,
    0.382683432365090f, 0.290284677254462f, 0.195090322016128f, 0.0980171403295606f};

__device__ __forceinline__ constexpr int brev(int x, int bits) {
    int r = 0;
    for (int i = 0; i < bits; ++i) { r = (r << 1) | (x & 1); x >>= 1; }
    return r;
}

__device__ __forceinline__ float vadd(float a, float b) { return a + b; }
__device__ __forceinline__ float vsub(float a, float b) { return a - b; }
__device__ __forceinline__ float vmul(float a, float s) { return a * s; }
__device__ __forceinline__ float2 vadd(float2 a, float2 b) { return make_float2(a.x + b.x, a.y + b.y); }
__device__ __forceinline__ float2 vsub(float2 a, float2 b) { return make_float2(a.x - b.x, a.y - b.y); }
__device__ __forceinline__ float2 vmul(float2 a, float s) { return make_float2(a.x * s, a.y * s); }

// in-register DIF FFT (sign +), output bit-reversed: re/im[j] = z[brev(j)]
template <int NP, typename V>
__device__ __forceinline__ void fft_dif(V* re, V* im) {
#pragma unroll
    for (int h = NP / 2; h >= 1; h >>= 1) {
#pragma unroll
        for (int b = 0; b < NP; b += 2 * h) {
#pragma unroll
            for (int k = 0; k < h; ++k) {
                V ur = re[b + k], ui = im[b + k];
                V vr = re[b + k + h], vi = im[b + k + h];
                V dr = vsub(ur, vr), di = vsub(ui, vi);
                re[b + k] = vadd(ur, vr);
                im[b + k] = vadd(ui, vi);
                float wr = W64R[k * (32 / h)], wi = W64I[k * (32 / h)];
                re[b + k + h] = vsub(vmul(dr, wr), vmul(di, wi));
                im[b + k + h] = vadd(vmul(dr, wi), vmul(di, wr));
            }
        }
    }
}

// ---- init: tw2048[k]=e^{2pi i k/2048}; Z coeff tables (double precision) --
__global__ void tw_init_kernel(float2* __restrict__ tw2048,
                               float2* __restrict__ ca, float2* __restrict__ cb,
                               float2* __restrict__ cc, float2* __restrict__ cd) {
    int k = blockIdx.x * TT + threadIdx.x;   // 8 blocks x 256 = 2048
    const double s = 0.5 / 4096.0;
    double aw = M_PI * (double)k / 2048.0;
    double wr = cos(aw), wi = sin(aw);
    double a1 = M_PI * (double)k / 8192.0;
    double e1r = cos(a1), e1i = sin(a1);
    double a2 = M_PI * (double)(k + 2048) / 8192.0;
    double e2r = cos(a2), e2i = sin(a2);
    double Ar = s * ((1.0 - wi) * e1r - wr * e1i);
    double Ai = s * ((1.0 - wi) * e1i + wr * e1r);
    double Br = (k == 0) ? 0.0 : Ai;
    double Bi = (k == 0) ? 0.0 : -Ar;
    double Cr = s * ((1.0 + wi) * e2r + wr * e2i);
    double Ci = s * ((1.0 + wi) * e2i - wr * e2r);
    ca[k] = make_float2((float)Ar, (float)Ai);
    cb[k] = make_float2((float)Br, (float)Bi);
    cc[k] = make_float2((float)Cr, (float)Ci);
    cd[k] = make_float2((float)Ci, (float)-Cr);
    double at = M_PI * (double)k / 1024.0;
    tw2048[k] = make_float2((float)cos(at), (float)sin(at));
}

// ---- column pass A: 1 column per thread, 32-pt FFT over k2 ----------------
// grid (64,16) x block (64,4): 4096 cols x 64 k1 -> 4096 waves = 16/CU.
// launch_bounds min-waves=1: allocator must NOT cap below the 64 live regs.
__global__ __launch_bounds__(TT, 1) void col_a_kernel(
    const float* __restrict__ x,
    const float2* __restrict__ ca, const float2* __restrict__ cb,
    const float2* __restrict__ cc, const float2* __restrict__ cd,
    const float2* __restrict__ tw2048, float2* __restrict__ T1) {
    int c = blockIdx.x * 64 + threadIdx.x;       // real column index [0,4096)
    int k1 = blockIdx.y * 4 + threadIdx.y;       // [0,64)
    float fr[32], fi[32];
#pragma unroll
    for (int k2 = 0; k2 < 32; ++k2) {
        int k = k1 + 64 * k2;
        float xa = x[(size_t)k * 4096 + c];
        float xb = x[(size_t)((4096 - k) & 4095) * 4096 + c];
        float xc = x[(size_t)(2048 + k) * 4096 + c];
        float xd = x[(size_t)(2048 - k) * 4096 + c];
        float2 A = ca[k], B = cb[k], C = cc[k], D = cd[k];
        fr[k2] = A.x * xa + B.x * xb + C.x * xc + D.x * xd;
        fi[k2] = A.y * xa + B.y * xb + C.y * xc + D.y * xd;
    }
    fft_dif<32, float>(fr, fi);
#pragma unroll
    for (int j = 0; j < 32; ++j) {
        int n2 = brev(j, 5);
        float2 w = tw2048[k1 * n2];
        float2 o = make_float2(fr[j] * w.x - fi[j] * w.y,
                               fr[j] * w.y + fi[j] * w.x);
        T1[(size_t)(k1 * 32 + n2) * 4096 + c] = o;
    }
}

// ---- column pass B: 64-pt FFT as DIT inside one wave ----------------------
// Lanes l and l+32 hold the SAME column (c = bx*32 + (l&31)) with opposite
// k1 parity. Each half does a 32-pt register FFT; the odd half applies
// W64^n; combine via __shfl_xor(.,32): z[n]=E+WO (lower), z[n+32]=E-WO
// (upper). No LDS, no barriers, no idle lanes.
// grid (128,8) x 256: wave w of block handles n2 = by*4 + w.
__global__ __launch_bounds__(TT, 1) void col_b_kernel(
    const float2* __restrict__ T1, float* __restrict__ out) {
    const int t = threadIdx.x;
    const int wv = t >> 6;             // wave id -> n2 sub-index
    const int l = t & 63;
    const int par = l >> 5;            // k1 parity of this lane
    const int c = blockIdx.x * 32 + (l & 31);
    const int n2 = blockIdx.y * 4 + wv;
    float fr[32], fi[32];
#pragma unroll
    for (int a = 0; a < 32; ++a) {
        int k1 = 2 * a + par;
        float2 v = T1[(size_t)(k1 * 32 + n2) * 4096 + c];
        fr[a] = v.x; fi[a] = v.y;
    }
    fft_dif<32, float>(fr, fi);        // E (par=0) or O (par=1), bit-rev j
    const float sgn = par ? -1.0f : 1.0f;
#pragma unroll
    for (int j = 0; j < 32; ++j) {
        int n = brev(j, 5);
        // odd half: multiply by W64^n (lower half: identity)
        float wr = par ? W64R[n] : 1.0f;
        float wi = par ? W64I[n] : 0.0f;
        float vr = fr[j] * wr - fi[j] * wi;
        float vi = fr[j] * wi + fi[j] * wr;
        float orr = __shfl_xor(vr, 32, 64);
        float oii = __shfl_xor(vi, 32, 64);
        // lower lane: own=E, other=WO -> E+WO ; upper: own=WO, other=E -> E-WO
        float zr = orr + sgn * vr;
        float zi = oii + sgn * vi;
        int n1 = par ? (n + 32) : n;
        int m = 32 * n1 + n2;
        int r_re = (n1 < 32) ? 4 * m     : 8191 - 4 * m;
        int r_im = (n1 < 32) ? 4 * m + 2 : 8189 - 4 * m;
        out[(size_t)r_re * 4096 + c] = zr;
        out[(size_t)r_im * 4096 + c] = zi;
    }
}

// ---- radix-8 DFT (sign +) --------------------------------------------------
#define C_SQ2 0.70710678118654752440f
__device__ __forceinline__ void radix8(const float* ar, const float* ai,
                                       float* tr, float* ti) {
    float s04r = ar[0] + ar[4], s04i = ai[0] + ai[4];
    float d04r = ar[0] - ar[4], d04i = ai[0] - ai[4];
    float s26r = ar[2] + ar[6], s26i = ai[2] + ai[6];
    float d26r = ar[2] - ar[6], d26i = ai[2] - ai[6];
    float E0r = s04r + s26r, E0i = s04i + s26i;
    float E1r = d04r - d26i, E1i = d04i + d26r;
    float E2r = s04r - s26r, E2i = s04i - s26i;
    float E3r = d04r + d26i, E3i = d04i - d26r;
    float s15r = ar[1] + ar[5], s15i = ai[1] + ai[5];
    float d15r = ar[1] - ar[5], d15i = ai[1] - ai[5];
    float s37r = ar[3] + ar[7], s37i = ai[3] + ai[7];
    float d37r = ar[3] - ar[7], d37i = ai[3] - ai[7];
    float O0r = s15r + s37r, O0i = s15i + s37i;
    float O1r = d15r - d37i, O1i = d15i + d37r;
    float O2r = s15r - s37r, O2i = s15i - s37i;
    float O3r = d15r + d37i, O3i = d15i - d37r;
    float W1r = C_SQ2 * (O1r - O1i), W1i = C_SQ2 * (O1r + O1i);
    float W2r = -O2i, W2i = O2r;
    float W3r = -C_SQ2 * (O3r + O3i), W3i = C_SQ2 * (O3r - O3i);
    tr[0] = E0r + O0r; ti[0] = E0i + O0i;
    tr[4] = E0r - O0r; ti[4] = E0i - O0i;
    tr[1] = E1r + W1r; ti[1] = E1i + W1i;
    tr[5] = E1r - W1r; ti[5] = E1i - W1i;
    tr[2] = E2r + W2r; ti[2] = E2i + W2i;
    tr[6] = E2r - W2r; ti[6] = E2i - W2i;
    tr[3] = E3r + W3r; ti[3] = E3i + W3i;
    tr[7] = E3r - W3r; ti[7] = E3i - W3i;
}

// ---- row pass: in-place per-row IDCT, float4 staged I/O -------------------
// pool: b0r[2112] b0i[2112] b1r[2176] b1i[2176]; staging overlays b1 region.
__global__ __launch_bounds__(TT) void idct_rows_kernel(
    const float2* __restrict__ ca, const float2* __restrict__ cb,
    const float2* __restrict__ cc, const float2* __restrict__ cd,
    const float2* __restrict__ tw2048, float* __restrict__ io) {
    __shared__ float pool[8576];
    float* b0r = pool;
    float* b0i = pool + 2112;
    float* b1r = pool + 4224;
    float* b1i = pool + 6400;
    float* stg = pool + 4224;   // 4096 floats, overlays b1 (free until stage B)
    const int t = threadIdx.x;
    float* __restrict__ xr = io + (size_t)blockIdx.x * 4096;

    // stage the row via float4 loads
#pragma unroll
    for (int u = 0; u < 4; ++u) {
        int idx = t + 256 * u;
        float4 v = ((const float4*)xr)[idx];
        *(float4*)&stg[4 * idx] = v;
    }
    __syncthreads();

    float zr[8], zi[8], tr[8], ti[8];
#pragma unroll
    for (int p = 0; p < 8; ++p) {
        int k = t + 256 * p;
        float xa = stg[k];
        float xb = stg[(4096 - k) & 4095];
        float xc = stg[2048 + k];
        float xd = stg[2048 - k];
        float2 A = ca[k], B = cb[k], C = cc[k], D = cd[k];
        zr[p] = A.x * xa + B.x * xb + C.x * xc + D.x * xd;
        zi[p] = A.y * xa + B.y * xb + C.y * xc + D.y * xd;
    }
    // stage A: m=1, j=t; write b0 at 8t+q+(t>>2)
    radix8(zr, zi, tr, ti);
    {
        int baseA = 8 * t + (t >> 2);
        b0r[baseA] = tr[0]; b0i[baseA] = ti[0];
#pragma unroll
        for (int q = 1; q < 8; ++q) {
            float2 w = tw2048[(t * q) & 2047];
            b0r[baseA + q] = w.x * tr[q] - w.y * ti[q];
            b0i[baseA + q] = w.x * ti[q] + w.y * tr[q];
        }
    }
    __syncthreads();
    // stage B: m=8; read b0 (t+(t>>5))+264p, write b1 68j+k +8q+(q>>1)
    {
        float ar[8], ai[8];
        int rb = t + (t >> 5);
#pragma unroll
        for (int p = 0; p < 8; ++p) { ar[p] = b0r[rb + 264 * p]; ai[p] = b0i[rb + 264 * p]; }
        radix8(ar, ai, tr, ti);
        int j = t >> 3, k = t & 7, wj = 8 * j;
        int baseB = 68 * j + k;
        b1r[baseB] = tr[0]; b1i[baseB] = ti[0];
#pragma unroll
        for (int q = 1; q < 8; ++q) {
            int off = baseB + 8 * q + (q >> 1);
            float2 w = tw2048[(wj * q) & 2047];
            b1r[off] = w.x * tr[q] - w.y * ti[q];
            b1i[off] = w.x * ti[q] + w.y * tr[q];
        }
    }
    __syncthreads();
    // stage C: m=64; read b1 (t+(t>>4))+272p, write b0 528j+66q+k+(k>>5)
    {
        float ar[8], ai[8];
        int rb = t + (t >> 4);
#pragma unroll
        for (int p = 0; p < 8; ++p) { ar[p] = b1r[rb + 272 * p]; ai[p] = b1i[rb + 272 * p]; }
        radix8(ar, ai, tr, ti);
        int j = t >> 6, wj = 64 * j, k = t & 63;
        int baseC = 528 * j + k + (k >> 5);
        b0r[baseC] = tr[0]; b0i[baseC] = ti[0];
#pragma unroll
        for (int q = 1; q < 8; ++q) {
            int off = baseC + 66 * q;
            float2 w = tw2048[(wj * q) & 2047];
            b0r[off] = w.x * tr[q] - w.y * ti[q];
            b0i[off] = w.x * ti[q] + w.y * tr[q];
        }
    }
    __syncthreads();
    // stage D: m=512 radix-4, tw=1; read b0 (b+(b>>5))+528s, write b1 (b+(b>>4))+544s
#pragma unroll
    for (int u = 0; u < 2; ++u) {
        int b = t + 256 * u;
        int rb = b + (b >> 5);
        int wb = b + (b >> 4);
        float a0r = b0r[rb], a0i = b0i[rb];
        float a1r = b0r[rb + 528], a1i = b0i[rb + 528];
        float a2r = b0r[rb + 1056], a2i = b0i[rb + 1056];
        float a3r = b0r[rb + 1584], a3i = b0i[rb + 1584];
        float s02r = a0r + a2r, s02i = a0i + a2i;
        float d02r = a0r - a2r, d02i = a0i - a2i;
        float s13r = a1r + a3r, s13i = a1i + a3i;
        float d13r = a1r - a3r, d13i = a1i - a3i;
        b1r[wb] = s02r + s13r;          b1i[wb] = s02i + s13i;
        b1r[wb + 544] = d02r - d13i;    b1i[wb + 544] = d02i + d13r;
        b1r[wb + 1088] = s02r - s13r;   b1i[wb + 1088] = s02i - s13i;
        b1r[wb + 1632] = d02r + d13i;   b1i[wb + 1632] = d02i - d13r;
    }
    __syncthreads();
    // epilogue: out[4s..4s+3] = {Re z[s], Im z[2047-s], Im z[s], Re z[2047-s]}
#pragma unroll
    for (int i = 0; i < 4; ++i) {
        int s = t + 256 * i;
        int l2 = 2047 - s;
        int ms = s + (s >> 4);
        int ml = l2 + (l2 >> 4);
        float4 o = make_float4(b1r[ms], b1i[ml], b1i[ms], b1r[ml]);
        *(float4*)&xr[4 * s] = o;
    }
}

extern "C" void kernel_launch(void* const* d_in, const int* in_sizes, int n_in,
                              void* d_out, int out_size, void* d_ws, size_t ws_size,
                              hipStream_t stream) {
    const float* x = (const float*)d_in[0];
    float* out = (float*)d_out;

    float2* tw2048 = (float2*)d_ws;
    float2* ca = (float2*)((char*)d_ws + 1 * 16384);
    float2* cb = (float2*)((char*)d_ws + 2 * 16384);
    float2* cc = (float2*)((char*)d_ws + 3 * 16384);
    float2* cd = (float2*)((char*)d_ws + 4 * 16384);
    float2* T1 = (float2*)((char*)d_ws + (1 << 20));   // 64 MB

    tw_init_kernel<<<8, TT, 0, stream>>>(tw2048, ca, cb, cc, cd);
    col_a_kernel<<<dim3(64, 16), dim3(64, 4), 0, stream>>>(x, ca, cb, cc, cd, tw2048, T1);
    col_b_kernel<<<dim3(128, 8), TT, 0, stream>>>(T1, out);
    idct_rows_kernel<<<4096, TT, 0, stream>>>(ca, cb, cc, cd, tw2048, out);
}

// Round 4
// 188.412 us; speedup vs baseline: 1.1597x; 1.0361x over previous
//
#include <hip/hip_runtime.h>
#include <math.h>

// 2D IDCT 4096x4096.
// colA: Z-build + 32-pt FFT as DIT split across the two halves of one wave
//       (lane l <-> l+32 = even/odd k2 of the SAME column); 16-pt register
//       FFT per half + __shfl_xor combine. fr/fi[16] keeps VGPR<=64 so
//       8 waves/SIMD are resident; grid = 2048 blocks = 8/CU.
// colB: 64-pt FFT as DIT split the same way over k1; no LDS, no barriers.
// rows: in-place LDS Stockham radix-8/8/8/4 with float4 staged I/O.

#define TT 256

constexpr float W64R[32] = {
    1.0f, 0.995184726672197f, 0.980785280403230f, 0.956940335732209f,
    0.923879532511287f, 0.881921264348355f, 0.831469612302545f, 0.773010453362737f,
    0.707106781186548f, 0.634393284163645f, 0.555570233019602f, 0.471396736825998f,
    0.382683432365090f, 0.290284677254462f, 0.195090322016128f, 0.0980171403295606f,
    0.0f, -0.0980171403295606f, -0.195090322016128f, -0.290284677254462f,
    -0.382683432365090f, -0.471396736825998f, -0.555570233019602f, -0.634393284163645f,
    -0.707106781186548f, -0.773010453362737f, -0.831469612302545f, -0.881921264348355f,
    -0.923879532511287f, -0.956940335732209f, -0.980785280403230f, -0.995184726672197f};
constexpr float W64I[32] = {
    0.0f, 0.0980171403295606f, 0.195090322016128f, 0.290284677254462f,
    0.382683432365090f, 0.471396736825998f, 0.555570233019602f, 0.634393284163645f,
    0.707106781186548f, 0.773010453362737f, 0.831469612302545f, 0.881921264348355f,
    0.923879532511287f, 0.956940335732209f, 0.980785280403230f, 0.995184726672197f,
    1.0f, 0.995184726672197f, 0.980785280403230f, 0.956940335732209f,
    0.923879532511287f, 0.881921264348355f, 0.831469612302545f, 0.773010453362737f,
    0.707106781186548f, 0.634393284163645f, 0.555570233019602f, 0.471396736825998f,
    0.382683432365090f, 0.290284677254462f, 0.195090322016128f, 0.0980171403295606f};

__device__ __forceinline__ constexpr int brev(int x, int bits) {
    int r = 0;
    for (int i = 0; i < bits; ++i) { r = (r << 1) | (x & 1); x >>= 1; }
    return r;
}

__device__ __forceinline__ float vadd(float a, float b) { return a + b; }
__device__ __forceinline__ float vsub(float a, float b) { return a - b; }
__device__ __forceinline__ float vmul(float a, float s) { return a * s; }

// in-register DIF FFT (sign +), output bit-reversed: re/im[j] = z[brev(j)]
// twiddle table indexing k*(32/h) yields e^{2pi i k / (2h)} for any NP<=64.
template <int NP, typename V>
__device__ __forceinline__ void fft_dif(V* re, V* im) {
#pragma unroll
    for (int h = NP / 2; h >= 1; h >>= 1) {
#pragma unroll
        for (int b = 0; b < NP; b += 2 * h) {
#pragma unroll
            for (int k = 0; k < h; ++k) {
                V ur = re[b + k], ui = im[b + k];
                V vr = re[b + k + h], vi = im[b + k + h];
                V dr = vsub(ur, vr), di = vsub(ui, vi);
                re[b + k] = vadd(ur, vr);
                im[b + k] = vadd(ui, vi);
                float wr = W64R[k * (32 / h)], wi = W64I[k * (32 / h)];
                re[b + k + h] = vsub(vmul(dr, wr), vmul(di, wi));
                im[b + k + h] = vadd(vmul(dr, wi), vmul(di, wr));
            }
        }
    }
}

// ---- init: tw2048[k]=e^{2pi i k/2048}; Z coeff tables (double precision) --
// cAC[k] = (Ar, Ai, Cr, Ci) packed; B=(Ai,-Ar)*(k!=0), D=(Ci,-Cr) derived.
__global__ void tw_init_kernel(float2* __restrict__ tw2048,
                               float2* __restrict__ ca, float2* __restrict__ cb,
                               float2* __restrict__ cc, float2* __restrict__ cd,
                               float4* __restrict__ cAC) {
    int k = blockIdx.x * TT + threadIdx.x;   // 8 blocks x 256 = 2048
    const double s = 0.5 / 4096.0;
    double aw = M_PI * (double)k / 2048.0;
    double wr = cos(aw), wi = sin(aw);
    double a1 = M_PI * (double)k / 8192.0;
    double e1r = cos(a1), e1i = sin(a1);
    double a2 = M_PI * (double)(k + 2048) / 8192.0;
    double e2r = cos(a2), e2i = sin(a2);
    double Ar = s * ((1.0 - wi) * e1r - wr * e1i);
    double Ai = s * ((1.0 - wi) * e1i + wr * e1r);
    double Br = (k == 0) ? 0.0 : Ai;
    double Bi = (k == 0) ? 0.0 : -Ar;
    double Cr = s * ((1.0 + wi) * e2r + wr * e2i);
    double Ci = s * ((1.0 + wi) * e2i - wr * e2r);
    ca[k] = make_float2((float)Ar, (float)Ai);
    cb[k] = make_float2((float)Br, (float)Bi);
    cc[k] = make_float2((float)Cr, (float)Ci);
    cd[k] = make_float2((float)Ci, (float)-Cr);
    cAC[k] = make_float4((float)Ar, (float)Ai, (float)Cr, (float)Ci);
    double at = M_PI * (double)k / 1024.0;
    tw2048[k] = make_float2((float)cos(at), (float)sin(at));
}

// ---- column pass A: 32-pt FFT as DIT inside one wave ----------------------
// Lanes l and l+32 hold the SAME column c = bx*32 + (l&31); par = l>>5 is
// the k2 parity. Each half: Z-build for its 16 k2 + 16-pt register FFT;
// odd half applies W32^n = W64[2n]; combine via __shfl_xor(.,32):
// X[n] = E + W*O (lower), X[n+16] = E - W*O (upper).
// grid (128,16) x block (64,4): 8192 waves = 32/CU over >=1 generation.
__global__ __launch_bounds__(TT) void col_a_kernel(
    const float* __restrict__ x, const float4* __restrict__ cAC,
    const float2* __restrict__ tw2048, float2* __restrict__ T1) {
    const int l = threadIdx.x;
    const int par = l >> 5;                  // k2 parity of this lane
    const int c = blockIdx.x * 32 + (l & 31);
    const int k1 = blockIdx.y * 4 + threadIdx.y;   // [0,64)
    float fr[16], fi[16];
#pragma unroll
    for (int a = 0; a < 16; ++a) {
        int k2 = 2 * a + par;
        int k = k1 + 64 * k2;
        float xa = x[(size_t)k * 4096 + c];
        float xb = x[(size_t)((4096 - k) & 4095) * 4096 + c];
        float xc = x[(size_t)(2048 + k) * 4096 + c];
        float xd = x[(size_t)(2048 - k) * 4096 + c];
        float4 P = cAC[k];                   // (Ar, Ai, Cr, Ci)
        float bs = (k == 0) ? 0.0f : 1.0f;   // B = bs*(Ai, -Ar), D = (Ci, -Cr)
        fr[a] = P.x * xa + bs * P.y * xb + P.z * xc + P.w * xd;
        fi[a] = P.y * xa - bs * P.x * xb + P.w * xc - P.z * xd;
    }
    fft_dif<16, float>(fr, fi);              // E (par=0) or O (par=1), bit-rev j
    const float sgn = par ? -1.0f : 1.0f;
#pragma unroll
    for (int j = 0; j < 16; ++j) {
        int n = brev(j, 4);
        float wr = par ? W64R[2 * n] : 1.0f; // W32^n on the odd branch
        float wi = par ? W64I[2 * n] : 0.0f;
        float vr = fr[j] * wr - fi[j] * wi;
        float vi = fr[j] * wi + fi[j] * wr;
        float orr = __shfl_xor(vr, 32, 64);
        float oii = __shfl_xor(vi, 32, 64);
        float zr = orr + sgn * vr;           // lower: E+WO ; upper: E-WO
        float zi = oii + sgn * vi;
        int n2 = par ? (n + 16) : n;
        float2 w2 = tw2048[k1 * n2];
        float2 o = make_float2(zr * w2.x - zi * w2.y,
                               zr * w2.y + zi * w2.x);
        T1[(size_t)(k1 * 32 + n2) * 4096 + c] = o;
    }
}

// ---- column pass B: 64-pt FFT as DIT inside one wave ----------------------
// Lanes l and l+32 hold the SAME column (c = bx*32 + (l&31)) with opposite
// k1 parity. Each half does a 32-pt register FFT; the odd half applies
// W64^n; combine via __shfl_xor(.,32): z[n]=E+WO (lower), z[n+32]=E-WO
// (upper). No LDS, no barriers, no idle lanes.
// grid (128,8) x 256: wave w of block handles n2 = by*4 + w.
__global__ __launch_bounds__(TT, 1) void col_b_kernel(
    const float2* __restrict__ T1, float* __restrict__ out) {
    const int t = threadIdx.x;
    const int wv = t >> 6;             // wave id -> n2 sub-index
    const int l = t & 63;
    const int par = l >> 5;            // k1 parity of this lane
    const int c = blockIdx.x * 32 + (l & 31);
    const int n2 = blockIdx.y * 4 + wv;
    float fr[32], fi[32];
#pragma unroll
    for (int a = 0; a < 32; ++a) {
        int k1 = 2 * a + par;
        float2 v = T1[(size_t)(k1 * 32 + n2) * 4096 + c];
        fr[a] = v.x; fi[a] = v.y;
    }
    fft_dif<32, float>(fr, fi);        // E (par=0) or O (par=1), bit-rev j
    const float sgn = par ? -1.0f : 1.0f;
#pragma unroll
    for (int j = 0; j < 32; ++j) {
        int n = brev(j, 5);
        // odd half: multiply by W64^n (lower half: identity)
        float wr = par ? W64R[n] : 1.0f;
        float wi = par ? W64I[n] : 0.0f;
        float vr = fr[j] * wr - fi[j] * wi;
        float vi = fr[j] * wi + fi[j] * wr;
        float orr = __shfl_xor(vr, 32, 64);
        float oii = __shfl_xor(vi, 32, 64);
        // lower lane: own=E, other=WO -> E+WO ; upper: own=WO, other=E -> E-WO
        float zr = orr + sgn * vr;
        float zi = oii + sgn * vi;
        int n1 = par ? (n + 32) : n;
        int m = 32 * n1 + n2;
        int r_re = (n1 < 32) ? 4 * m     : 8191 - 4 * m;
        int r_im = (n1 < 32) ? 4 * m + 2 : 8189 - 4 * m;
        out[(size_t)r_re * 4096 + c] = zr;
        out[(size_t)r_im * 4096 + c] = zi;
    }
}

// ---- radix-8 DFT (sign +) --------------------------------------------------
#define C_SQ2 0.70710678118654752440f
__device__ __forceinline__ void radix8(const float* ar, const float* ai,
                                       float* tr, float* ti) {
    float s04r = ar[0] + ar[4], s04i = ai[0] + ai[4];
    float d04r = ar[0] - ar[4], d04i = ai[0] - ai[4];
    float s26r = ar[2] + ar[6], s26i = ai[2] + ai[6];
    float d26r = ar[2] - ar[6], d26i = ai[2] - ai[6];
    float E0r = s04r + s26r, E0i = s04i + s26i;
    float E1r = d04r - d26i, E1i = d04i + d26r;
    float E2r = s04r - s26r, E2i = s04i - s26i;
    float E3r = d04r + d26i, E3i = d04i - d26r;
    float s15r = ar[1] + ar[5], s15i = ai[1] + ai[5];
    float d15r = ar[1] - ar[5], d15i = ai[1] - ai[5];
    float s37r = ar[3] + ar[7], s37i = ai[3] + ai[7];
    float d37r = ar[3] - ar[7], d37i = ai[3] - ai[7];
    float O0r = s15r + s37r, O0i = s15i + s37i;
    float O1r = d15r - d37i, O1i = d15i + d37r;
    float O2r = s15r - s37r, O2i = s15i - s37i;
    float O3r = d15r + d37i, O3i = d15i - d37r;
    float W1r = C_SQ2 * (O1r - O1i), W1i = C_SQ2 * (O1r + O1i);
    float W2r = -O2i, W2i = O2r;
    float W3r = -C_SQ2 * (O3r + O3i), W3i = C_SQ2 * (O3r - O3i);
    tr[0] = E0r + O0r; ti[0] = E0i + O0i;
    tr[4] = E0r - O0r; ti[4] = E0i - O0i;
    tr[1] = E1r + W1r; ti[1] = E1i + W1i;
    tr[5] = E1r - W1r; ti[5] = E1i - W1i;
    tr[2] = E2r + W2r; ti[2] = E2i + W2i;
    tr[6] = E2r - W2r; ti[6] = E2i - W2i;
    tr[3] = E3r + W3r; ti[3] = E3i + W3i;
    tr[7] = E3r - W3r; ti[7] = E3i - W3i;
}

// ---- row pass: in-place per-row IDCT, float4 staged I/O -------------------
// pool: b0r[2112] b0i[2112] b1r[2176] b1i[2176]; staging overlays b1 region.
__global__ __launch_bounds__(TT) void idct_rows_kernel(
    const float2* __restrict__ ca, const float2* __restrict__ cb,
    const float2* __restrict__ cc, const float2* __restrict__ cd,
    const float2* __restrict__ tw2048, float* __restrict__ io) {
    __shared__ float pool[8576];
    float* b0r = pool;
    float* b0i = pool + 2112;
    float* b1r = pool + 4224;
    float* b1i = pool + 6400;
    float* stg = pool + 4224;   // 4096 floats, overlays b1 (free until stage B)
    const int t = threadIdx.x;
    float* __restrict__ xr = io + (size_t)blockIdx.x * 4096;

    // stage the row via float4 loads
#pragma unroll
    for (int u = 0; u < 4; ++u) {
        int idx = t + 256 * u;
        float4 v = ((const float4*)xr)[idx];
        *(float4*)&stg[4 * idx] = v;
    }
    __syncthreads();

    float zr[8], zi[8], tr[8], ti[8];
#pragma unroll
    for (int p = 0; p < 8; ++p) {
        int k = t + 256 * p;
        float xa = stg[k];
        float xb = stg[(4096 - k) & 4095];
        float xc = stg[2048 + k];
        float xd = stg[2048 - k];
        float2 A = ca[k], B = cb[k], C = cc[k], D = cd[k];
        zr[p] = A.x * xa + B.x * xb + C.x * xc + D.x * xd;
        zi[p] = A.y * xa + B.y * xb + C.y * xc + D.y * xd;
    }
    // stage A: m=1, j=t; write b0 at 8t+q+(t>>2)
    radix8(zr, zi, tr, ti);
    {
        int baseA = 8 * t + (t >> 2);
        b0r[baseA] = tr[0]; b0i[baseA] = ti[0];
#pragma unroll
        for (int q = 1; q < 8; ++q) {
            float2 w = tw2048[(t * q) & 2047];
            b0r[baseA + q] = w.x * tr[q] - w.y * ti[q];
            b0i[baseA + q] = w.x * ti[q] + w.y * tr[q];
        }
    }
    __syncthreads();
    // stage B: m=8; read b0 (t+(t>>5))+264p, write b1 68j+k +8q+(q>>1)
    {
        float ar[8], ai[8];
        int rb = t + (t >> 5);
#pragma unroll
        for (int p = 0; p < 8; ++p) { ar[p] = b0r[rb + 264 * p]; ai[p] = b0i[rb + 264 * p]; }
        radix8(ar, ai, tr, ti);
        int j = t >> 3, k = t & 7, wj = 8 * j;
        int baseB = 68 * j + k;
        b1r[baseB] = tr[0]; b1i[baseB] = ti[0];
#pragma unroll
        for (int q = 1; q < 8; ++q) {
            int off = baseB + 8 * q + (q >> 1);
            float2 w = tw2048[(wj * q) & 2047];
            b1r[off] = w.x * tr[q] - w.y * ti[q];
            b1i[off] = w.x * ti[q] + w.y * tr[q];
        }
    }
    __syncthreads();
    // stage C: m=64; read b1 (t+(t>>4))+272p, write b0 528j+66q+k+(k>>5)
    {
        float ar[8], ai[8];
        int rb = t + (t >> 4);
#pragma unroll
        for (int p = 0; p < 8; ++p) { ar[p] = b1r[rb + 272 * p]; ai[p] = b1i[rb + 272 * p]; }
        radix8(ar, ai, tr, ti);
        int j = t >> 6, wj = 64 * j, k = t & 63;
        int baseC = 528 * j + k + (k >> 5);
        b0r[baseC] = tr[0]; b0i[baseC] = ti[0];
#pragma unroll
        for (int q = 1; q < 8; ++q) {
            int off = baseC + 66 * q;
            float2 w = tw2048[(wj * q) & 2047];
            b0r[off] = w.x * tr[q] - w.y * ti[q];
            b0i[off] = w.x * ti[q] + w.y * tr[q];
        }
    }
    __syncthreads();
    // stage D: m=512 radix-4, tw=1; read b0 (b+(b>>5))+528s, write b1 (b+(b>>4))+544s
#pragma unroll
    for (int u = 0; u < 2; ++u) {
        int b = t + 256 * u;
        int rb = b + (b >> 5);
        int wb = b + (b >> 4);
        float a0r = b0r[rb], a0i = b0i[rb];
        float a1r = b0r[rb + 528], a1i = b0i[rb + 528];
        float a2r = b0r[rb + 1056], a2i = b0i[rb + 1056];
        float a3r = b0r[rb + 1584], a3i = b0i[rb + 1584];
        float s02r = a0r + a2r, s02i = a0i + a2i;
        float d02r = a0r - a2r, d02i = a0i - a2i;
        float s13r = a1r + a3r, s13i = a1i + a3i;
        float d13r = a1r - a3r, d13i = a1i - a3i;
        b1r[wb] = s02r + s13r;          b1i[wb] = s02i + s13i;
        b1r[wb + 544] = d02r - d13i;    b1i[wb + 544] = d02i + d13r;
        b1r[wb + 1088] = s02r - s13r;   b1i[wb + 1088] = s02i - s13i;
        b1r[wb + 1632] = d02r + d13i;   b1i[wb + 1632] = d02i - d13r;
    }
    __syncthreads();
    // epilogue: out[4s..4s+3] = {Re z[s], Im z[2047-s], Im z[s], Re z[2047-s]}
#pragma unroll
    for (int i = 0; i < 4; ++i) {
        int s = t + 256 * i;
        int l2 = 2047 - s;
        int ms = s + (s >> 4);
        int ml = l2 + (l2 >> 4);
        float4 o = make_float4(b1r[ms], b1i[ml], b1i[ms], b1r[ml]);
        *(float4*)&xr[4 * s] = o;
    }
}

extern "C" void kernel_launch(void* const* d_in, const int* in_sizes, int n_in,
                              void* d_out, int out_size, void* d_ws, size_t ws_size,
                              hipStream_t stream) {
    const float* x = (const float*)d_in[0];
    float* out = (float*)d_out;

    float2* tw2048 = (float2*)d_ws;
    float2* ca = (float2*)((char*)d_ws + 1 * 16384);
    float2* cb = (float2*)((char*)d_ws + 2 * 16384);
    float2* cc = (float2*)((char*)d_ws + 3 * 16384);
    float2* cd = (float2*)((char*)d_ws + 4 * 16384);
    float4* cAC = (float4*)((char*)d_ws + 5 * 16384);   // 32 KB
    float2* T1 = (float2*)((char*)d_ws + (1 << 20));    // 64 MB

    tw_init_kernel<<<8, TT, 0, stream>>>(tw2048, ca, cb, cc, cd, cAC);
    col_a_kernel<<<dim3(128, 16), dim3(64, 4), 0, stream>>>(x, cAC, tw2048, T1);
    col_b_kernel<<<dim3(128, 8), TT, 0, stream>>>(T1, out);
    idct_rows_kernel<<<4096, TT, 0, stream>>>(ca, cb, cc, cd, tw2048, out);
}